// Round 2
// baseline (610.979 us; speedup 1.0000x reference)
//
#include <hip/hip_runtime.h>

// CircularUpsample2: circular pad (3) + upfirdn2d(up=2, k=4x4 FIR, pad=(2,1)) + crop.
// Direct gather form: out[Y][X] = sum_{a,b in {0,1}} x[(my-2+a)&127][(mx-2+b)&127]
//                                  * k[(a?py:2+py)][(b?px:2+px)]
// with my=Y>>1, py=Y&1 (same for x-dim). Derived from lhs_dilation conv algebra.

#define H 128
#define W 128
#define OH 256
#define OW 256

__global__ __launch_bounds__(256) void CircularUpsample2_kernel(
    const float* __restrict__ x, const float* __restrict__ k,
    float* __restrict__ out, int bc_count) {
  int idx = blockIdx.x * 256 + threadIdx.x;
  int t    = idx & 63;        // 4-output-col group: cols [4t, 4t+4)
  int rest = idx >> 6;
  int my   = rest & (H - 1);  // output rows 2my, 2my+1
  int bc   = rest >> 7;
  if (bc >= bc_count) return;

  const float* __restrict__ xp = x + (size_t)bc * (H * W);
  float* __restrict__ op = out + (size_t)bc * (OH * OW);

  int r0 = (my - 2) & (H - 1);
  int r1 = (my - 1) & (H - 1);
  int c0 = (2 * t - 2) & (W - 1);
  int c1 = (2 * t - 1) & (W - 1);
  int c2 = (2 * t) & (W - 1);

  float x00 = xp[r0 * W + c0], x01 = xp[r0 * W + c1], x02 = xp[r0 * W + c2];
  float x10 = xp[r1 * W + c0], x11 = xp[r1 * W + c1], x12 = xp[r1 * W + c2];

  // 4x4 kernel, row-major. Uniform address -> scalar loads.
  float k00 = k[0],  k01 = k[1],  k02 = k[2],  k03 = k[3];
  float k10 = k[4],  k11 = k[5],  k12 = k[6],  k13 = k[7];
  float k20 = k[8],  k21 = k[9],  k22 = k[10], k23 = k[11];
  float k30 = k[12], k31 = k[13], k32 = k[14], k33 = k[15];

  // Even output row (py=0): kernel rows (2 for r0-tap, 0 for r1-tap)
  float4 e;
  e.x = x00 * k22 + x01 * k20 + x10 * k02 + x11 * k00;  // X=4t+0 (px=0: cols 2,0)
  e.y = x00 * k23 + x01 * k21 + x10 * k03 + x11 * k01;  // X=4t+1 (px=1: cols 3,1)
  e.z = x01 * k22 + x02 * k20 + x11 * k02 + x12 * k00;  // X=4t+2
  e.w = x01 * k23 + x02 * k21 + x11 * k03 + x12 * k01;  // X=4t+3

  // Odd output row (py=1): kernel rows (3 for r0-tap, 1 for r1-tap)
  float4 o;
  o.x = x00 * k32 + x01 * k30 + x10 * k12 + x11 * k10;
  o.y = x00 * k33 + x01 * k31 + x10 * k13 + x11 * k11;
  o.z = x01 * k32 + x02 * k30 + x11 * k12 + x12 * k10;
  o.w = x01 * k33 + x02 * k31 + x11 * k13 + x12 * k11;

  *reinterpret_cast<float4*>(op + (size_t)(2 * my) * OW + 4 * t) = e;
  *reinterpret_cast<float4*>(op + (size_t)(2 * my + 1) * OW + 4 * t) = o;
}

extern "C" void kernel_launch(void* const* d_in, const int* in_sizes, int n_in,
                              void* d_out, int out_size, void* d_ws, size_t ws_size,
                              hipStream_t stream) {
  const float* x = (const float*)d_in[0];
  const float* k = (const float*)d_in[1];
  float* out = (float*)d_out;

  int bc_count = in_sizes[0] / (H * W);             // 8*256 = 2048
  int total_threads = bc_count * (H) * (W / 2);     // one thread per (bc, my, t)
  int nblocks = (total_threads + 255) / 256;        // 65536 for the bench shape

  CircularUpsample2_kernel<<<nblocks, 256, 0, stream>>>(x, k, out, bc_count);
}